// Round 8
// baseline (11840.838 us; speedup 1.0000x reference)
//
#include <hip/hip_runtime.h>
#include <hip/hip_bf16.h>
#include <cstdint>
#include <cstddef>

#define LOG2E 1.44269504088896340736f

using f32x4 = __attribute__((ext_vector_type(4))) float;
using s16x8 = __attribute__((ext_vector_type(8))) short;

static __device__ __forceinline__ float bf2f(unsigned short u) {
  union { unsigned int i; float f; } v; v.i = ((unsigned int)u) << 16; return v.f;
}
static __device__ __forceinline__ unsigned short f2bf(float f) {
  union { float f; unsigned int i; } v; v.f = f;
  unsigned int r = v.i + 0x7fffu + ((v.i >> 16) & 1u);
  return (unsigned short)(r >> 16);
}
static __device__ __forceinline__ float wredmax(float v) {
  #pragma unroll
  for (int m = 32; m > 0; m >>= 1) v = fmaxf(v, __shfl_xor(v, m, 64));
  return v;
}
static __device__ __forceinline__ float wredsum(float v) {
  #pragma unroll
  for (int m = 32; m > 0; m >>= 1) v += __shfl_xor(v, m, 64);
  return v;
}

// ---------------------------------------------------------------------------
// Transform kernel (unchanged).
// ---------------------------------------------------------------------------
__global__ void ktrans(const float* __restrict__ W1, const float* __restrict__ b1,
                       const float* __restrict__ Wih_in, const float* __restrict__ bih,
                       const float* __restrict__ Whh, const float* __restrict__ bhh,
                       const float* __restrict__ Wfc, const float* __restrict__ bfc,
                       const float* __restrict__ yhist,
                       unsigned short* __restrict__ WB1, unsigned short* __restrict__ WBhh,
                       unsigned short* __restrict__ WB1e, float* __restrict__ b1s,
                       float* __restrict__ Wihs, float* __restrict__ gbias,
                       float* __restrict__ yh2)
{
  int idx = blockIdx.x * 256 + threadIdx.x;
  const float TS = 2.f * LOG2E;
  if (idx < 131072) {                       // WB1: (k,e')
    int k = idx >> 8, e = idx & 255;
    WB1[((k >> 3) * 256 + e) * 8 + (k & 7)] = f2bf(TS * W1[e * 768 + k]);
    return;
  }
  idx -= 131072;
  if (idx < 262144) {                       // WBhh: (k,j)
    int k = idx >> 10, j = idx & 1023;
    float sc = ((j >> 8) == 2) ? TS : -LOG2E;
    WBhh[((k >> 3) * 1024 + j) * 8 + (k & 7)] = f2bf(sc * Whh[j * 256 + k]);
    return;
  }
  idx -= 262144;
  if (idx < 65536) {                        // WB1e: (k,e'), x part
    int k = idx >> 8, e = idx & 255;
    WB1e[((k >> 3) * 256 + e) * 8 + (k & 7)] = f2bf(TS * W1[e * 768 + 512 + k]);
    return;
  }
  idx -= 65536;
  if (idx < 256) { b1s[idx] = TS * b1[idx]; return; }
  idx -= 256;
  if (idx < 2048) {                         // Wihs (j,o)
    int j = idx >> 1;
    float sc = ((j >> 8) == 2) ? TS : -LOG2E;
    Wihs[idx] = sc * Wih_in[idx];
    return;
  }
  idx -= 2048;
  if (idx < 1024) {
    int j = idx;
    float sc = ((j >> 8) == 2) ? TS : -LOG2E;
    gbias[j] = sc * (bih[j] + bhh[j]);
    return;
  }
  idx -= 1024;
  if (idx < 4096) {                         // yh2 (b,o)
    int bq = idx >> 1, o = idx & 1;
    float a = bfc[o];
    for (int t = 0; t < 64; ++t) a = fmaf(yhist[bq * 64 + t], Wfc[o * 320 + 256 + t], a);
    yh2[idx] = a;
    return;
  }
}

// ---------------------------------------------------------------------------
// Precompute kernel (unchanged, correctness-proven).
// ---------------------------------------------------------------------------
__global__ __launch_bounds__(256, 4) void kpre(
    const float* __restrict__ x, const unsigned short* __restrict__ WB1e,
    const float* __restrict__ Wfc,
    unsigned short* __restrict__ P, float* __restrict__ ey)
{
  __shared__ __align__(16) unsigned short xs[16384];
  const int bq = blockIdx.x;
  const int tid = threadIdx.x;
  const int w = tid >> 6, lane = tid & 63;
  const float* __restrict__ xb = x + (size_t)bq * 16384;

  #pragma unroll 4
  for (int it = 0; it < 16; ++it) {
    int idx = it * 256 + tid;
    float4 v = *(const float4*)(xb + (size_t)idx * 4);
    int t = idx >> 6, e0 = (idx & 63) * 4;
    unsigned long long pk = (unsigned long long)f2bf(v.x)
        | ((unsigned long long)f2bf(v.y) << 16)
        | ((unsigned long long)f2bf(v.z) << 32)
        | ((unsigned long long)f2bf(v.w) << 48);
    int ba = (t * 512 + e0 * 2) ^ ((t & 7) << 4);
    *(unsigned long long*)((char*)xs + ba) = pk;
  }
  __syncthreads();

  const int mt = w;
  const int fgrp = lane >> 4, fcol = lane & 15;
  const int trow = mt * 16 + fcol;
  s16x8 af[8];
  #pragma unroll
  for (int kb = 0; kb < 8; ++kb) {
    int e = kb * 32 + fgrp * 8;
    int ba = (trow * 512 + e * 2) ^ ((trow & 7) << 4);
    af[kb] = *(const s16x8*)((char*)xs + ba);
  }
  __syncthreads();

  unsigned short* __restrict__ Pst = xs;
  #pragma unroll
  for (int nt = 0; nt < 16; ++nt) {
    s16x8 bfr[8];
    #pragma unroll
    for (int kb = 0; kb < 8; ++kb)
      bfr[kb] = *(const s16x8*)&WB1e[(size_t)((kb * 4 + fgrp) * 256 + nt * 16 + fcol) * 8];
    f32x4 acc = {0.f, 0.f, 0.f, 0.f};
    #pragma unroll
    for (int kb = 0; kb < 8; ++kb)
      acc = __builtin_amdgcn_mfma_f32_16x16x32_bf16(af[kb], bfr[kb], acc, 0, 0, 0);
    const int ep = nt * 16 + fcol;
    #pragma unroll
    for (int r = 0; r < 4; ++r)
      Pst[(mt * 16 + fgrp * 4 + r) * 256 + ep] = f2bf(acc[r]);
  }
  __syncthreads();

  unsigned int* __restrict__ Pd = (unsigned int*)(P + (size_t)bq * 16384);
  #pragma unroll 4
  for (int d = tid; d < 8192; d += 256) {
    int f = d * 2;
    int ec = f >> 9, t = (f >> 3) & 63, i0 = f & 7;
    unsigned int lo = Pst[t * 256 + ec * 8 + i0];
    unsigned int hi = Pst[t * 256 + ec * 8 + i0 + 1];
    Pd[d] = lo | (hi << 16);
  }

  if (tid < 128) {
    int t = tid >> 1, o = tid & 1;
    float a = 0.f;
    const float* __restrict__ xr = xb + t * 256;
    const float* __restrict__ wr = Wfc + o * 320;
    #pragma unroll 4
    for (int e = 0; e < 256; ++e) a = fmaf(xr[e], wr[e], a);
    ey[((size_t)bq * 64 + t) * 2 + o] = a;
  }
}

// ---------------------------------------------------------------------------
// Recurrence v8: 256 threads / 4 waves (VGPR budget 256 per the empirical
// 65536/threads rule). Wave owns 2 rows: P = 32 named reg chunks (128 VGPR)
// + 16 LDS chunks/row. Gates+pointwise fused per col-group; hcA double-
// buffered. 3 barriers/step.
// ---------------------------------------------------------------------------
#define SIG(X) __builtin_amdgcn_rcpf(1.f + __builtin_amdgcn_exp2f(X))

#define SCCH(PV, EC) do { \
  const float4 qa_ = *(const float4*)(qr_ + (EC) * 8); \
  const float4 qc_ = *(const float4*)(qr_ + (EC) * 8 + 4); \
  const float4 wa_ = *(const float4*)(w2f + (EC) * 8); \
  const float4 wc_ = *(const float4*)(w2f + (EC) * 8 + 4); \
  a0 = fmaf(wa_.x, SIG(bf2f((unsigned short)(PV)[0]) + qa_.x), a0); \
  a1 = fmaf(wa_.y, SIG(bf2f((unsigned short)(PV)[1]) + qa_.y), a1); \
  a2 = fmaf(wa_.z, SIG(bf2f((unsigned short)(PV)[2]) + qa_.z), a2); \
  a3 = fmaf(wa_.w, SIG(bf2f((unsigned short)(PV)[3]) + qa_.w), a3); \
  a0 = fmaf(wc_.x, SIG(bf2f((unsigned short)(PV)[4]) + qc_.x), a0); \
  a1 = fmaf(wc_.y, SIG(bf2f((unsigned short)(PV)[5]) + qc_.y), a1); \
  a2 = fmaf(wc_.z, SIG(bf2f((unsigned short)(PV)[6]) + qc_.z), a2); \
  a3 = fmaf(wc_.w, SIG(bf2f((unsigned short)(PV)[7]) + qc_.w), a3); \
} while (0)

#define SCLX(RR, U) do { \
  const s16x8 pv_ = *(const s16x8*)&Pl[RR][(U) - 16][lane][0]; \
  SCCH(pv_, U); \
} while (0)

// full score + softmax + yt for one row; PP = pA or pB (16 reg chunks)
#define SCOREROW(PP, RR, EYV, YH0V, YH1V) do { \
  const float* __restrict__ qr_ = &qf[RR][0]; \
  float a0 = 0.f, a1 = 0.f, a2 = 0.f, a3 = 0.f; \
  SCCH(PP##0, 0);   SCCH(PP##1, 1);   SCCH(PP##2, 2);   SCCH(PP##3, 3); \
  SCCH(PP##4, 4);   SCCH(PP##5, 5);   SCCH(PP##6, 6);   SCCH(PP##7, 7); \
  SCCH(PP##8, 8);   SCCH(PP##9, 9);   SCCH(PP##10, 10); SCCH(PP##11, 11); \
  SCCH(PP##12, 12); SCCH(PP##13, 13); SCCH(PP##14, 14); SCCH(PP##15, 15); \
  SCLX(RR, 16); SCLX(RR, 17); SCLX(RR, 18); SCLX(RR, 19); \
  SCLX(RR, 20); SCLX(RR, 21); SCLX(RR, 22); SCLX(RR, 23); \
  SCLX(RR, 24); SCLX(RR, 25); SCLX(RR, 26); SCLX(RR, 27); \
  SCLX(RR, 28); SCLX(RR, 29); SCLX(RR, 30); SCLX(RR, 31); \
  float sc_ = -2.f * ((a0 + a1) + (a2 + a3)); \
  float mx_ = wredmax(sc_); \
  float e_ = __builtin_amdgcn_exp2f((sc_ - mx_) * LOG2E); \
  float sm_ = wredsum(e_); \
  float al_ = e_ * __builtin_amdgcn_rcpf(sm_); \
  if (s == 63) scAl[RR][lane] = al_; \
  float y0_ = wredsum(al_ * (EYV).x); \
  float y1_ = wredsum(al_ * (EYV).y); \
  if (lane == 0) { yt[RR][0] = y0_ + (YH0V); yt[RR][1] = y1_ + (YH1V); } \
} while (0)

#define PWX(R, CV) { \
  const int row_ = drow0 + (R); \
  const float y0_ = yt[row_][0], y1_ = yt[row_][1]; \
  const float gi_ = G0[R] + fmaf(wI_.x, y0_, wI_.y * y1_); \
  const float gf_ = G1[R] + fmaf(wF_.x, y0_, wF_.y * y1_); \
  const float gg_ = G2[R] + fmaf(wG_.x, y0_, wG_.y * y1_); \
  const float go_ = G3[R] + fmaf(wO_.x, y0_, wO_.y * y1_); \
  const float si_ = SIG(gi_); \
  const float sf_ = SIG(gf_); \
  const float tg_ = 1.f - 2.f * SIG(gg_); \
  const float so_ = SIG(go_); \
  const float cn_ = sf_ * (CV) + si_ * tg_; \
  (CV) = cn_; \
  const float th_ = 1.f - 2.f * SIG(2.f * LOG2E * cn_); \
  const float hn_ = so_ * th_; \
  hcW[((jj_ >> 3) * 8 + row_) * 8 + (jj_ & 7)] = f2bf(hn_); \
  hcW[((32 + (jj_ >> 3)) * 8 + row_) * 8 + (jj_ & 7)] = f2bf(cn_); \
  if (s == 63) hF[row_ * 256 + jj_] = hn_; \
}

// one col-group: 16 j-cols x 4 gates, K=256 MFMA, fused pointwise
#define GATECG(CG, C0, C1, C2, C3) do { \
  const int jj_ = wv * 64 + (CG) * 16 + fcol; \
  const float gI_ = gbias[jj_],       gF_ = gbias[256 + jj_]; \
  const float gG_ = gbias[512 + jj_], gO_ = gbias[768 + jj_]; \
  f32x4 G0 = {gI_, gI_, gI_, gI_}; \
  f32x4 G1 = {gF_, gF_, gF_, gF_}; \
  f32x4 G2 = {gG_, gG_, gG_, gG_}; \
  f32x4 G3 = {gO_, gO_, gO_, gO_}; \
  _Pragma("unroll") \
  for (int kb = 0; kb < 8; ++kb) { \
    const s16x8 a_ = *(const s16x8*)&hcR[((kb * 4 + fgrp) * 8 + frow) * 8]; \
    const size_t ko_ = (size_t)(kb * 4 + fgrp) * 8192; \
    const s16x8 b0_ = *(const s16x8*)&WBhh[ko_ + (size_t)jj_ * 8]; \
    const s16x8 b1_ = *(const s16x8*)&WBhh[ko_ + (size_t)(256 + jj_) * 8]; \
    const s16x8 b2_ = *(const s16x8*)&WBhh[ko_ + (size_t)(512 + jj_) * 8]; \
    const s16x8 b3_ = *(const s16x8*)&WBhh[ko_ + (size_t)(768 + jj_) * 8]; \
    G0 = __builtin_amdgcn_mfma_f32_16x16x32_bf16(a_, b0_, G0, 0, 0, 0); \
    G1 = __builtin_amdgcn_mfma_f32_16x16x32_bf16(a_, b1_, G1, 0, 0, 0); \
    G2 = __builtin_amdgcn_mfma_f32_16x16x32_bf16(a_, b2_, G2, 0, 0, 0); \
    G3 = __builtin_amdgcn_mfma_f32_16x16x32_bf16(a_, b3_, G3, 0, 0, 0); \
  } \
  if (lane < 32) { \
    const float2 wI_ = *(const float2*)&Wihs[2 * jj_]; \
    const float2 wF_ = *(const float2*)&Wihs[2 * (256 + jj_)]; \
    const float2 wG_ = *(const float2*)&Wihs[2 * (512 + jj_)]; \
    const float2 wO_ = *(const float2*)&Wihs[2 * (768 + jj_)]; \
    PWX(0, C0) PWX(1, C1) PWX(2, C2) PWX(3, C3) \
  } \
} while (0)

#define PLA(U) const s16x8 pA##U = *(const s16x8*)(PbA + (size_t)(U) * 512 + lane * 8);
#define PLB(U) const s16x8 pB##U = *(const s16x8*)(PbB + (size_t)(U) * 512 + lane * 8);

__global__ __launch_bounds__(256) void krecur(
    const float* __restrict__ x, const float* __restrict__ w2g,
    const unsigned short* __restrict__ WB1, const unsigned short* __restrict__ WBhh,
    const float* __restrict__ Wihs, const float* __restrict__ gbias,
    const float* __restrict__ b1s, const float* __restrict__ yh2,
    const float* __restrict__ ey, const unsigned short* __restrict__ P,
    const float* __restrict__ Wfin, const float* __restrict__ bfin,
    float* __restrict__ out)
{
  __shared__ __align__(16) unsigned short Pl[8][16][64][8]; // 128 KB (ec 16..31); hF/ctx alias
  __shared__ __align__(16) unsigned short hcA[2][4096];     // 16 KB double-buffered state
  __shared__ __align__(16) float qf[8][256];                // 8 KB
  __shared__ __align__(16) float w2f[256];                  // 1 KB
  __shared__ __align__(16) float b1f[256];                  // 1 KB
  __shared__ __align__(16) float scAl[8][64];               // 2 KB
  __shared__ float yt[8][2];                                // ~156 KB total

  float* const hF   = (float*)&Pl[0][0][0][0];  // [8][256] f32
  float* const ctxS = hF + 2048;                // [8][256] f32

  const int tid = threadIdx.x;
  const int wv = tid >> 6, lane = tid & 63;
  const int gbase = blockIdx.x * 8;
  const int r0 = 2 * wv, r1 = 2 * wv + 1;
  const int gb0 = gbase + r0, gb1 = gbase + r1;

  for (int i = tid; i < 8192; i += 256) ((unsigned short*)hcA)[i] = 0;
  if (tid < 256) { w2f[tid] = w2g[tid]; b1f[tid] = b1s[tid]; }
  // P LDS chunks (ec 16..31) for all 8 rows
  for (int i = tid; i < 8192; i += 256) {
    int rw = i >> 10, rem = i & 1023, ch = rem >> 6, t = rem & 63;
    *(s16x8*)&Pl[rw][ch][t][0] =
        *(const s16x8*)(P + (size_t)(gbase + rw) * 16384 + (size_t)(16 + ch) * 512 + t * 8);
  }

  const int frow = lane & 7;
  const int fgrp = lane >> 4;
  const int fcol = lane & 15;
  const int drow0 = fgrp * 4;

  // P reg chunks ec 0..15 for both rows: 32 named s16x8 = 128 VGPR
  const unsigned short* __restrict__ PbA = P + (size_t)gb0 * 16384;
  const unsigned short* __restrict__ PbB = P + (size_t)gb1 * 16384;
  PLA(0)  PLA(1)  PLA(2)  PLA(3)  PLA(4)  PLA(5)  PLA(6)  PLA(7)
  PLA(8)  PLA(9)  PLA(10) PLA(11) PLA(12) PLA(13) PLA(14) PLA(15)
  PLB(0)  PLB(1)  PLB(2)  PLB(3)  PLB(4)  PLB(5)  PLB(6)  PLB(7)
  PLB(8)  PLB(9)  PLB(10) PLB(11) PLB(12) PLB(13) PLB(14) PLB(15)

  const float2 ey0 = *(const float2*)(ey + ((size_t)gb0 * 64 + lane) * 2);
  const float2 ey1 = *(const float2*)(ey + ((size_t)gb1 * 64 + lane) * 2);
  const float yh00 = yh2[gb0 * 2], yh01 = yh2[gb0 * 2 + 1];
  const float yh10 = yh2[gb1 * 2], yh11 = yh2[gb1 * 2 + 1];

  float c00 = 0.f, c01 = 0.f, c02 = 0.f, c03 = 0.f;
  float c10 = 0.f, c11 = 0.f, c12 = 0.f, c13 = 0.f;
  float c20 = 0.f, c21 = 0.f, c22 = 0.f, c23 = 0.f;
  float c30 = 0.f, c31 = 0.f, c32 = 0.f, c33 = 0.f;

  __syncthreads();

  for (int s = 0; s < 64; ++s) {
    const unsigned short* __restrict__ hcR = hcA[s & 1];
    unsigned short* __restrict__ hcW = hcA[(s + 1) & 1];

    // ---- phase1: q (4 N-tiles/wave, K=512 over h|c) ----
    {
      f32x4 q0 = {0.f,0.f,0.f,0.f}, q1 = {0.f,0.f,0.f,0.f};
      f32x4 q2 = {0.f,0.f,0.f,0.f}, q3 = {0.f,0.f,0.f,0.f};
      const int cb = wv * 64 + fcol;
      #pragma unroll
      for (int kb = 0; kb < 16; ++kb) {
        const s16x8 a_ = *(const s16x8*)&hcR[((kb * 4 + fgrp) * 8 + frow) * 8];
        const size_t kk_ = (size_t)(kb * 4 + fgrp) * 256;
        const s16x8 b0_ = *(const s16x8*)&WB1[(kk_ + cb) * 8];
        const s16x8 b1_ = *(const s16x8*)&WB1[(kk_ + cb + 16) * 8];
        const s16x8 b2_ = *(const s16x8*)&WB1[(kk_ + cb + 32) * 8];
        const s16x8 b3_ = *(const s16x8*)&WB1[(kk_ + cb + 48) * 8];
        q0 = __builtin_amdgcn_mfma_f32_16x16x32_bf16(a_, b0_, q0, 0, 0, 0);
        q1 = __builtin_amdgcn_mfma_f32_16x16x32_bf16(a_, b1_, q1, 0, 0, 0);
        q2 = __builtin_amdgcn_mfma_f32_16x16x32_bf16(a_, b2_, q2, 0, 0, 0);
        q3 = __builtin_amdgcn_mfma_f32_16x16x32_bf16(a_, b3_, q3, 0, 0, 0);
      }
      if (lane < 32) {
        #pragma unroll
        for (int r = 0; r < 4; ++r) {
          qf[drow0 + r][cb]      = q0[r] + b1f[cb];
          qf[drow0 + r][cb + 16] = q1[r] + b1f[cb + 16];
          qf[drow0 + r][cb + 32] = q2[r] + b1f[cb + 32];
          qf[drow0 + r][cb + 48] = q3[r] + b1f[cb + 48];
        }
      }
    }
    __syncthreads();                                   // B1: qf ready

    // ---- phase2: full scores + softmax + yt for this wave's 2 rows ----
    SCOREROW(pA, r0, ey0, yh00, yh01);
    SCOREROW(pB, r1, ey1, yh10, yh11);
    __syncthreads();                                   // B2: yt ready

    // ---- phase3: gates MFMA + fused pointwise, 4 col-groups ----
    GATECG(0, c00, c01, c02, c03);
    GATECG(1, c10, c11, c12, c13);
    GATECG(2, c20, c21, c22, c23);
    GATECG(3, c30, c31, c32, c33);
    __syncthreads();                                   // B3: hcW ready
  }

  // ---- ctx (own rows; scAl from own wave, hF covered by last B3) ----
  #pragma unroll
  for (int ri = 0; ri < 2; ++ri) {
    const int rr = r0 + ri;
    const size_t gbr = gbase + rr;
    #pragma unroll
    for (int p = 0; p < 4; ++p) {
      const int e = p * 64 + lane;
      float a = 0.f;
      const float* __restrict__ xr = x + gbr * 16384 + e;
      #pragma unroll 8
      for (int t = 0; t < 64; ++t) a = fmaf(scAl[rr][t], xr[t * 256], a);
      ctxS[rr * 256 + e] = a;
    }
  }

  // ---- final: out = [h, ctx] @ W_final.T + b_final ----
  #pragma unroll
  for (int ri = 0; ri < 2; ++ri) {
    const int rr = r0 + ri;
    const int gbr = gbase + rr;
    float o0 = 0.f, o1 = 0.f;
    #pragma unroll
    for (int kk = 0; kk < 8; ++kk) {
      const int k = kk * 64 + lane;
      const float v = (k < 256) ? hF[rr * 256 + k] : ctxS[rr * 256 + (k - 256)];
      o0 = fmaf(v, Wfin[k], o0);
      o1 = fmaf(v, Wfin[512 + k], o1);
    }
    o0 = wredsum(o0);
    o1 = wredsum(o1);
    if (lane == 0) {
      out[gbr * 2 + 0] = o0 + bfin[0];
      out[gbr * 2 + 1] = o1 + bfin[1];
    }
  }
}

// ---------------------------------------------------------------------------
extern "C" void kernel_launch(void* const* d_in, const int* in_sizes, int n_in,
                              void* d_out, int out_size, void* d_ws, size_t ws_size,
                              hipStream_t stream) {
  const float* x    = (const float*)d_in[0];
  const float* yh   = (const float*)d_in[1];
  const float* W1   = (const float*)d_in[2];
  const float* b1   = (const float*)d_in[3];
  const float* w2   = (const float*)d_in[4];
  // d_in[5] = b2: softmax-invariant -> unused
  const float* Wih  = (const float*)d_in[6];
  const float* bih  = (const float*)d_in[7];
  const float* Whh  = (const float*)d_in[8];
  const float* bhh  = (const float*)d_in[9];
  const float* Wfc  = (const float*)d_in[10];
  const float* bfc  = (const float*)d_in[11];
  const float* Wfin = (const float*)d_in[12];
  const float* bfin = (const float*)d_in[13];

  char* ws = (char*)d_ws;
  unsigned short* P    = (unsigned short*)(ws + 0);          // 67,108,864 B
  unsigned short* WB1  = (unsigned short*)(ws + 67108864);   //    262,144 B
  unsigned short* WBhh = (unsigned short*)(ws + 67371008);   //    524,288 B
  unsigned short* WB1e = (unsigned short*)(ws + 67895296);   //    131,072 B
  float* b1s   = (float*)(ws + 68026368);                    //      1,024 B
  float* Wihs  = (float*)(ws + 68027392);                    //      8,192 B
  float* gbias = (float*)(ws + 68035584);                    //      4,096 B
  float* yh2   = (float*)(ws + 68039680);                    //     16,384 B
  float* ey    = (float*)(ws + 68056064);                    //  1,048,576 B -> 69,104,640 total

  ktrans<<<1821, 256, 0, stream>>>(W1, b1, Wih, bih, Whh, bhh, Wfc, bfc, yh,
                                   WB1, WBhh, WB1e, b1s, Wihs, gbias, yh2);
  kpre<<<2048, 256, 0, stream>>>(x, WB1e, Wfc, P, ey);
  krecur<<<256, 256, 0, stream>>>(x, w2, WB1, WBhh, Wihs, gbias, b1s, yh2, ey, P,
                                  Wfin, bfin, (float*)d_out);
}